// Round 2
// baseline (1036.153 us; speedup 1.0000x reference)
//
#include <hip/hip_runtime.h>
#include <hip/hip_bf16.h>

typedef float float4v __attribute__((ext_vector_type(4)));
typedef __bf16 bf16x8 __attribute__((ext_vector_type(8)));

#define MFMA16(a, b, c) __builtin_amdgcn_mfma_f32_16x16x32_bf16(a, b, c, 0, 0, 0)

__device__ __forceinline__ float fsigmoid(float x) {
    return __builtin_amdgcn_rcpf(1.0f + __expf(-x));
}
__device__ __forceinline__ float ftanh_(float x) {
    float e = __expf(2.0f * x);
    return 1.0f - 2.0f * __builtin_amdgcn_rcpf(e + 1.0f);
}
__device__ __forceinline__ float softplusf(float x) {
    return fmaxf(x, 0.0f) + __logf(1.0f + __expf(-fabsf(x)));
}

// ---------------------------------------------------------------------------
// Kernel 1: GRU over friend_x with COMPENSATED bf16 MFMA (hi/lo split on x, W
// and h; each product = 3 MFMAs). 16 rows/block, 272 blocks packed by
// descending lf via n = (63 - p/68) + 64*(p%68) so long sequences start first.
// Weights (hi+lo, both matrices) live in 384 VGPRs as B-frags. One barrier
// per step; x prefetched one step ahead; h carried fp32 in C-layout regs.
// ---------------------------------------------------------------------------
__global__ __launch_bounds__(256, 1)
void gru_kernel(const float* __restrict__ friend_x,
                const float* __restrict__ W_ih, const float* __restrict__ W_hh,
                const float* __restrict__ b_ih, const float* __restrict__ b_hh,
                const int* __restrict__ fmask,
                float* __restrict__ friend_out)
{
    // 8 buffers x 2048 bf16 (16 rows x 128 k, A-frag linear layout) = 32KB
    __shared__ __align__(16) __bf16 lds[8 * 2048];
    __shared__ int s_lf[16];
    __shared__ int s_n[16];

    const int tid = threadIdx.x;
    const int wv = tid >> 6;
    const int lane = tid & 63;
    const int cn = lane & 15;   // col within 16-tile
    const int qq = lane >> 4;   // quad

    __bf16* const XH0 = lds;
    __bf16* const XH1 = lds + 2048;
    __bf16* const XL0 = lds + 2 * 2048;
    __bf16* const XL1 = lds + 3 * 2048;
    __bf16* const HH0 = lds + 4 * 2048;
    __bf16* const HH1 = lds + 5 * 2048;
    __bf16* const HL0 = lds + 6 * 2048;
    __bf16* const HL1 = lds + 7 * 2048;

    // row -> n mapping + per-row lf (robust, from mask)
    if (tid < 16) {
        const int p = blockIdx.x * 16 + tid;
        const int v = p / 68;
        const int j = p - v * 68;
        const int n = (63 - v) + 64 * j;
        s_n[tid] = n;
        const int* mp = fmask + (long)n * 64;
        int s = 0;
        for (int i = 0; i < 64; ++i) s += mp[i];
        s_lf[tid] = s;
    }

    // zero h buffers (both, hi+lo)
    {
        bf16x8 z8;
#pragma unroll
        for (int j = 0; j < 8; ++j) z8[j] = (__bf16)0.0f;
        for (int i = tid; i < 4 * 2048 / 8; i += 256) ((bf16x8*)HH0)[i] = z8;
    }

    // ---- weights -> registers as B-frags, hi/lo compensated ----
    bf16x8 wihh[3][2][4], wihl[3][2][4], whhh[3][2][4], whhl[3][2][4];
#pragma unroll
    for (int gate = 0; gate < 3; ++gate)
#pragma unroll
        for (int ct = 0; ct < 2; ++ct) {
            const int row = gate * 128 + wv * 32 + ct * 16 + cn;
#pragma unroll
            for (int c = 0; c < 4; ++c) {
                const float* p = W_ih + row * 128 + c * 32 + qq * 8;
                float4v u0 = *(const float4v*)p;
                float4v u1 = *(const float4v*)(p + 4);
                bf16x8 fh, fl;
#pragma unroll
                for (int j = 0; j < 4; ++j) {
                    __bf16 h0 = (__bf16)u0[j]; fh[j] = h0; fl[j] = (__bf16)(u0[j] - (float)h0);
                    __bf16 h1 = (__bf16)u1[j]; fh[j + 4] = h1; fl[j + 4] = (__bf16)(u1[j] - (float)h1);
                }
                wihh[gate][ct][c] = fh; wihl[gate][ct][c] = fl;
                const float* q = W_hh + row * 128 + c * 32 + qq * 8;
                float4v v0 = *(const float4v*)q;
                float4v v1 = *(const float4v*)(q + 4);
                bf16x8 gh, gl;
#pragma unroll
                for (int j = 0; j < 4; ++j) {
                    __bf16 h0 = (__bf16)v0[j]; gh[j] = h0; gl[j] = (__bf16)(v0[j] - (float)h0);
                    __bf16 h1 = (__bf16)v1[j]; gh[j + 4] = h1; gl[j + 4] = (__bf16)(v1[j] - (float)h1);
                }
                whhh[gate][ct][c] = gh; whhl[gate][ct][c] = gl;
            }
        }

    float biasR[2], biasZ[2], biasIN[2], biasHN[2];
#pragma unroll
    for (int ct = 0; ct < 2; ++ct) {
        const int cc = wv * 32 + ct * 16 + cn;
        biasR[ct] = b_ih[cc] + b_hh[cc];
        biasZ[ct] = b_ih[128 + cc] + b_hh[128 + cc];
        biasIN[ct] = b_ih[256 + cc];
        biasHN[ct] = b_hh[256 + cc];
    }

    __syncthreads();   // s_n/s_lf + h zeros visible

    // staging role: thread tid covers slot-linear tid -> conflict-free b128
    //   c = tid>>6 (= wave), row = lane&15, s = lane>>4, k0 = c*32 + s*8
    const int srow = lane & 15;
    const int ss = lane >> 4;
    const float* xp = friend_x + (long)s_n[srow] * 8192 + wv * 32 + ss * 8;

    // hoist per-lane epilogue row data
    int lfA[4], nA[4];
#pragma unroll
    for (int r = 0; r < 4; ++r) { lfA[r] = s_lf[qq * 4 + r]; nA[r] = s_n[qq * 4 + r]; }
    int maxlf = 0;
    for (int i = 0; i < 16; ++i) maxlf = (s_lf[i] > maxlf) ? s_lf[i] : maxlf;

    // stage x_0 into buf 0
    {
        float4v u0 = *(const float4v*)(xp);
        float4v u1 = *(const float4v*)(xp + 4);
        bf16x8 fh, fl;
#pragma unroll
        for (int j = 0; j < 4; ++j) {
            __bf16 h0 = (__bf16)u0[j]; fh[j] = h0; fl[j] = (__bf16)(u0[j] - (float)h0);
            __bf16 h1 = (__bf16)u1[j]; fh[j + 4] = h1; fl[j + 4] = (__bf16)(u1[j] - (float)h1);
        }
        *(bf16x8*)&XH0[tid * 8] = fh;
        *(bf16x8*)&XL0[tid * 8] = fl;
    }
    __syncthreads();

    float hC[2][4];
#pragma unroll
    for (int ct = 0; ct < 2; ++ct)
#pragma unroll
        for (int r = 0; r < 4; ++r) hC[ct][r] = 0.0f;

    for (int t = 0; t < maxlf; ++t) {
        const int cur = t & 1;
        __bf16* const XHc = cur ? XH1 : XH0;
        __bf16* const XLc = cur ? XL1 : XL0;
        __bf16* const HHc = cur ? HH1 : HH0;
        __bf16* const HLc = cur ? HL1 : HL0;
        __bf16* const XHn = cur ? XH0 : XH1;
        __bf16* const XLn = cur ? XL0 : XL1;
        __bf16* const HHn = cur ? HH0 : HH1;
        __bf16* const HLn = cur ? HL0 : HL1;
        const bool pf = (t + 1 < maxlf);

        float4v u0, u1;
        if (pf) {   // prefetch x_{t+1}
            u0 = *(const float4v*)(xp + (t + 1) * 128);
            u1 = *(const float4v*)(xp + (t + 1) * 128 + 4);
        }

        float4v aR[2], aZ[2], aIN[2], aHN[2];
#pragma unroll
        for (int ct = 0; ct < 2; ++ct) {
            aR[ct] = (float4v){biasR[ct], biasR[ct], biasR[ct], biasR[ct]};
            aZ[ct] = (float4v){biasZ[ct], biasZ[ct], biasZ[ct], biasZ[ct]};
            aIN[ct] = (float4v){biasIN[ct], biasIN[ct], biasIN[ct], biasIN[ct]};
            aHN[ct] = (float4v){biasHN[ct], biasHN[ct], biasHN[ct], biasHN[ct]};
        }

#pragma unroll
        for (int c = 0; c < 4; ++c) {
            const int fo_ = (c * 64 + lane) * 8;
            bf16x8 xh = *(const bf16x8*)&XHc[fo_];
            bf16x8 xl = *(const bf16x8*)&XLc[fo_];
            bf16x8 hh = *(const bf16x8*)&HHc[fo_];
            bf16x8 hl = *(const bf16x8*)&HLc[fo_];
#pragma unroll
            for (int ct = 0; ct < 2; ++ct) {
                aR[ct] = MFMA16(xh, wihh[0][ct][c], aR[ct]);
                aR[ct] = MFMA16(xl, wihh[0][ct][c], aR[ct]);
                aR[ct] = MFMA16(xh, wihl[0][ct][c], aR[ct]);
                aR[ct] = MFMA16(hh, whhh[0][ct][c], aR[ct]);
                aR[ct] = MFMA16(hl, whhh[0][ct][c], aR[ct]);
                aR[ct] = MFMA16(hh, whhl[0][ct][c], aR[ct]);

                aZ[ct] = MFMA16(xh, wihh[1][ct][c], aZ[ct]);
                aZ[ct] = MFMA16(xl, wihh[1][ct][c], aZ[ct]);
                aZ[ct] = MFMA16(xh, wihl[1][ct][c], aZ[ct]);
                aZ[ct] = MFMA16(hh, whhh[1][ct][c], aZ[ct]);
                aZ[ct] = MFMA16(hl, whhh[1][ct][c], aZ[ct]);
                aZ[ct] = MFMA16(hh, whhl[1][ct][c], aZ[ct]);

                aIN[ct] = MFMA16(xh, wihh[2][ct][c], aIN[ct]);
                aIN[ct] = MFMA16(xl, wihh[2][ct][c], aIN[ct]);
                aIN[ct] = MFMA16(xh, wihl[2][ct][c], aIN[ct]);

                aHN[ct] = MFMA16(hh, whhh[2][ct][c], aHN[ct]);
                aHN[ct] = MFMA16(hl, whhh[2][ct][c], aHN[ct]);
                aHN[ct] = MFMA16(hh, whhl[2][ct][c], aHN[ct]);
            }
        }

        // gates (fp32) + h update + write h hi/lo into next buffers
#pragma unroll
        for (int ct = 0; ct < 2; ++ct) {
            const int col = wv * 32 + ct * 16 + cn;
            const int c2 = col >> 5, s2 = (col >> 3) & 3, j2 = col & 7;
#pragma unroll
            for (int reg = 0; reg < 4; ++reg) {
                const int row = qq * 4 + reg;
                float r = fsigmoid(aR[ct][reg]);
                float z = fsigmoid(aZ[ct][reg]);
                float nn = ftanh_(aIN[ct][reg] + r * aHN[ct][reg]);
                float h = (1.0f - z) * nn + z * hC[ct][reg];
                hC[ct][reg] = h;
                __bf16 hhi = (__bf16)h;
                __bf16 hlo = (__bf16)(h - (float)hhi);
                const int sl = (c2 * 64 + row + 16 * s2) * 8 + j2;
                HHn[sl] = hhi;
                HLn[sl] = hlo;
                if (t + 1 == lfA[reg])
                    friend_out[(long)nA[reg] * 128 + col] = h;
            }
        }

        if (pf) {   // commit prefetched x_{t+1}
            bf16x8 fh, fl;
#pragma unroll
            for (int j = 0; j < 4; ++j) {
                __bf16 h0 = (__bf16)u0[j]; fh[j] = h0; fl[j] = (__bf16)(u0[j] - (float)h0);
                __bf16 h1 = (__bf16)u1[j]; fh[j + 4] = h1; fl[j + 4] = (__bf16)(u1[j] - (float)h1);
            }
            *(bf16x8*)&XHn[tid * 8] = fh;
            *(bf16x8*)&XLn[tid * 8] = fl;
        }
        __syncthreads();
    }
}

// ---------------------------------------------------------------------------
// Kernel 2: per-sequence attention. score[l] = common_x[n,l,:].v where
// v = (cat @ W_friend^T) @ W_beta  -- collapses the NxLCxHxH matmul.
// Streams common_x only for l < lc (prefix mask). One WG per n. All fp32.
// ---------------------------------------------------------------------------
__global__ __launch_bounds__(256)
void attn_kernel(const float* __restrict__ self_x,
                 const float* __restrict__ common_x,
                 const float* __restrict__ common_time,
                 const float* __restrict__ W_friend,
                 const float* __restrict__ W_beta,
                 const int* __restrict__ csm,
                 const int* __restrict__ user_idx,
                 const float* __restrict__ friend_out,
                 float* __restrict__ tf)
{
    const int n = blockIdx.x;
    const int tid = threadIdx.x;
    const int wv = tid >> 6, lane = tid & 63;
    __shared__ __align__(16) float catf[256];
    __shared__ float sfs[128];
    __shared__ __align__(16) float vv[128];
    __shared__ float vpart[2][128];
    __shared__ int lcp[4];
    __shared__ int s_lc;
    __shared__ float wsum[4];

    if (tid < 128) catf[tid] = self_x[user_idx[n] * 128 + tid];
    else           catf[tid] = friend_out[(long)n * 128 + tid - 128];

    int mv = csm[(long)n * 256 + tid];
#pragma unroll
    for (int o = 32; o; o >>= 1) mv += __shfl_down(mv, o);
    if (lane == 0) lcp[wv] = mv;
    __syncthreads();
    if (tid == 0) s_lc = lcp[0] + lcp[1] + lcp[2] + lcp[3];

    // sf[h] = W_friend[h,:] . cat  (wave-dot, coalesced rows)
    float4v c4 = *(const float4v*)&catf[4 * lane];
    for (int i = 0; i < 32; ++i) {
        const int h = wv * 32 + i;
        float4v w4 = *(const float4v*)(W_friend + h * 256 + 4 * lane);
        float p = w4[0] * c4[0] + w4[1] * c4[1] + w4[2] * c4[2] + w4[3] * c4[3];
#pragma unroll
        for (int o = 1; o < 64; o <<= 1) p += __shfl_xor(p, o);
        if (lane == 0) sfs[h] = p;
    }
    __syncthreads();

    // v[col] = sum_h sf[h] * W_beta[h, col]  (coalesced W_beta rows)
    {
        const int col = tid & 127, half = tid >> 7;
        float acc = 0.f;
#pragma unroll 4
        for (int kk = 0; kk < 64; ++kk) {
            const int hh = kk * 2 + half;
            acc += sfs[hh] * W_beta[hh * 128 + col];
        }
        vpart[half][col] = acc;
    }
    __syncthreads();
    if (tid < 128) vv[tid] = vpart[0][tid] + vpart[1][tid];
    __syncthreads();

    const int lc = s_lc;
    const int lh = lane & 31, sub = lane >> 5;
    float4v v4 = *(const float4v*)&vv[4 * lh];
    const float* cxn = common_x + (long)n * 32768;
    const float* ctn = common_time + (long)n * 256;
    float acc = 0.f;
    for (int l0 = wv * 2 + sub; l0 < lc; l0 += 8) {
        float4v x4 = *(const float4v*)(cxn + l0 * 128 + 4 * lh);
        float p = x4[0] * v4[0] + x4[1] * v4[1] + x4[2] * v4[2] + x4[3] * v4[3];
#pragma unroll
        for (int o = 1; o < 32; o <<= 1) p += __shfl_xor(p, o);
        float contrib = softplusf(p) * __expf(1.0f - ctn[l0] * 1e-6f);
        if (lh == 0) acc += contrib;
    }
    acc += __shfl_xor(acc, 32);
    if (lane == 0) wsum[wv] = acc;
    __syncthreads();
    if (tid == 0) tf[n] = wsum[0] + wsum[1] + wsum[2] + wsum[3];
}

// ---------------------------------------------------------------------------
// Kernel 3: group softmax (over padded zeros, faithful) + weighted sum.
// ---------------------------------------------------------------------------
__global__ __launch_bounds__(128)
void agg_kernel(const float* __restrict__ tf, const float* __restrict__ fo,
                const int* __restrict__ gather_idx, const int* __restrict__ pad_mask,
                float* __restrict__ out)
{
    const int b = blockIdx.x, tid = threadIdx.x;
    __shared__ float tfp[16];
    __shared__ int gidx[16];
    __shared__ float pmf[16];
    if (tid < 16) {
        const int gg = gather_idx[b * 16 + tid];
        const int pp = pad_mask[b * 16 + tid];
        gidx[tid] = gg; pmf[tid] = (float)pp;
        tfp[tid] = pp ? tf[gg] : 0.0f;
    }
    __syncthreads();
    float m = tfp[0];
#pragma unroll
    for (int f = 1; f < 16; ++f) m = fmaxf(m, tfp[f]);
    float e[16]; float s = 0.f;
#pragma unroll
    for (int f = 0; f < 16; ++f) { e[f] = __expf(tfp[f] - m); s += e[f]; }
    const float inv = 1.0f / s;
    float acc = 0.f;
#pragma unroll
    for (int f = 0; f < 16; ++f) {
        if (pmf[f] != 0.0f) {
            const float w = e[f] * inv;
            acc += w * fo[(long)gidx[f] * 128 + tid];
        }
    }
    out[b * 128 + tid] = acc;
}

extern "C" void kernel_launch(void* const* d_in, const int* in_sizes, int n_in,
                              void* d_out, int out_size, void* d_ws, size_t ws_size,
                              hipStream_t stream)
{
    const float* self_x      = (const float*)d_in[0];
    const float* common_x    = (const float*)d_in[1];
    const float* common_time = (const float*)d_in[2];
    const float* friend_x    = (const float*)d_in[3];
    const float* W_ih        = (const float*)d_in[4];
    const float* W_hh        = (const float*)d_in[5];
    const float* b_ih        = (const float*)d_in[6];
    const float* b_hh        = (const float*)d_in[7];
    const float* W_friend    = (const float*)d_in[8];
    const float* W_beta      = (const float*)d_in[9];
    const int* fmask         = (const int*)d_in[10];
    const int* csm           = (const int*)d_in[11];
    const int* uidx          = (const int*)d_in[12];
    const int* gidx          = (const int*)d_in[13];
    const int* pmask         = (const int*)d_in[14];
    float* out = (float*)d_out;

    const int N = in_sizes[12];          // 4352
    const int B = in_sizes[0] / 128;     // 512

    float* fo_ws = (float*)d_ws;                       // [N,128] fp32
    float* tf_ws = fo_ws + (size_t)N * 128;            // [N] fp32

    gru_kernel<<<(N + 15) / 16, 256, 0, stream>>>(friend_x, W_ih, W_hh, b_ih, b_hh,
                                                  fmask, fo_ws);
    attn_kernel<<<N, 256, 0, stream>>>(self_x, common_x, common_time,
                                       W_friend, W_beta, csm, uidx, fo_ws, tf_ws);
    agg_kernel<<<B, 128, 0, stream>>>(tf_ws, fo_ws, gidx, pmask, out);

    (void)n_in; (void)out_size; (void)ws_size;
}